// Round 8
// baseline (672.714 us; speedup 1.0000x reference)
//
#include <hip/hip_runtime.h>

typedef unsigned short u16;
typedef unsigned char u8;
typedef __attribute__((ext_vector_type(4))) float f32x4;

#define B_ROWS 1024
#define DIM 512
#define QN 131072
#define TOPK 32
#define NCLS 10
#define TAUS 34.56f   /* 0.135 * 256 (both operands scaled x16) */
#define CAP 1024
#define FP8SCALE 16.0f
#define NCONV 256
#define GRID 768

#define S_VMCNT(N) asm volatile("s_waitcnt vmcnt(" #N ")" ::: "memory")
#define S_BAR() asm volatile("s_barrier" ::: "memory")
#define S_LGKM0() asm volatile("s_waitcnt lgkmcnt(0)" ::: "memory")

__device__ __forceinline__ void gload_lds16(const void* gsrc, void* ldst) {
  __builtin_amdgcn_global_load_lds(
      (const __attribute__((address_space(1))) void*)gsrc,
      (__attribute__((address_space(3))) void*)ldst, 16, 0, 0);
}

// pack 4 floats -> 4 fp8 e4m3 bytes (HW cvt). Same packer for A and B, so
// any byte-order convention cancels in the dot product.
__device__ __forceinline__ int pk4(float a, float b, float c, float d) {
  int w = __builtin_amdgcn_cvt_pk_fp8_f32(a, b, 0, false);
  w = __builtin_amdgcn_cvt_pk_fp8_f32(c, d, w, true);
  return w;
}

// =====================  fused producer/consumer megakernel  =================
// 768 persistent blocks (3/CU: 48 KiB LDS, launch_bounds(256,3)).
//   blocks 0..255  : normalize 4 x-rows each -> nctr; convert 4 memory
//                    panels each (fp32 -> fp8 x16, k-permuted) -> per-panel
//                    release flag; then join gemm.
//   all blocks     : per-XCD atomic tile tickets (XCD/L2 locality kept);
//                    acquire-spin on panel flag; R7-verbatim tile body.
// Deadlock-free under any occupancy: all waits target blocks 0..255 which
// are dispatched first. Output is order-invariant (rank-based selection in
// rescore), so dynamic scheduling preserves determinism.
__global__ __launch_bounds__(256, 3) void mega(const float* __restrict__ x,
                                               const float* __restrict__ mem,
                                               float* __restrict__ xn,
                                               u8* __restrict__ xnb8,
                                               u8* __restrict__ memb8,
                                               int* __restrict__ cnt,
                                               int* __restrict__ ccol,
                                               int* __restrict__ flags,
                                               int* __restrict__ tctr,
                                               int* __restrict__ nctr) {
  __shared__ __attribute__((aligned(16))) u8 As[3][8192];
  __shared__ __attribute__((aligned(16))) u8 Bs[3][8192];
  __shared__ int sh_t;
  int b = blockIdx.x;
  int tid = threadIdx.x;
  int xcd = b & 7;
  int local = b >> 3;
  int lane = tid & 63;
  int wv = tid >> 6;
  int wr = wv >> 1, wc = wv & 1;

  if (b < NCONV) {
    // ---- phase 0: normalize rows 4b..4b+3 (x -> xn fp32, xnb8 fp8 permuted)
    float* xs = (float*)&As[0][0];
    float* ws4 = (float*)&Bs[0][0];
    for (int row = b * 4; row < b * 4 + 4; ++row) {
      float2 v = ((const float2*)(x + (size_t)row * DIM))[tid];
      float ss = v.x * v.x + v.y * v.y;
      #pragma unroll
      for (int o = 32; o; o >>= 1) ss += __shfl_xor(ss, o);
      if ((tid & 63) == 0) ws4[tid >> 6] = ss;
      __syncthreads();
      float tot = ws4[0] + ws4[1] + ws4[2] + ws4[3];
      float scale = 1.0f / fmaxf(sqrtf(tot), 1e-12f);
      float2 o2; o2.x = v.x * scale; o2.y = v.y * scale;
      ((float2*)(xn + (size_t)row * DIM))[tid] = o2;
      xs[2 * tid] = o2.x; xs[2 * tid + 1] = o2.y;
      __syncthreads();
      if (tid < 32) {
        int c = tid >> 2, t4 = tid & 3;
        int k0 = c * 64 + t4 * 8;
        int4 w;
        w.x = pk4(xs[k0+0]*FP8SCALE, xs[k0+1]*FP8SCALE, xs[k0+2]*FP8SCALE, xs[k0+3]*FP8SCALE);
        w.y = pk4(xs[k0+4]*FP8SCALE, xs[k0+5]*FP8SCALE, xs[k0+6]*FP8SCALE, xs[k0+7]*FP8SCALE);
        w.z = pk4(xs[k0+32]*FP8SCALE, xs[k0+33]*FP8SCALE, xs[k0+34]*FP8SCALE, xs[k0+35]*FP8SCALE);
        w.w = pk4(xs[k0+36]*FP8SCALE, xs[k0+37]*FP8SCALE, xs[k0+38]*FP8SCALE, xs[k0+39]*FP8SCALE);
        ((int4*)(xnb8 + (size_t)row * DIM))[tid] = w;
      }
      __syncthreads();
    }
    __threadfence();
    __syncthreads();
    if (tid == 0) atomicAdd(nctr, 1);

    // ---- phase 1: convert 4 panels of this XCD's column range
    for (int j = 0; j < 4; ++j) {
      int P = xcd * 128 + local * 4 + j;
      const float* src0 = mem + (size_t)P * 128 * DIM;
      u8* dst0 = memb8 + (size_t)P * 128 * DIM;
      for (int s2 = tid; s2 < 4096; s2 += 256) {
        int r = s2 >> 5, sl = s2 & 31;
        int c = sl >> 2, t4 = sl & 3;
        const float* src = src0 + (size_t)r * DIM + c * 64 + t4 * 8;
        float4 f0 = ((const float4*)src)[0];
        float4 f1 = ((const float4*)src)[1];
        float4 f2 = ((const float4*)(src + 32))[0];
        float4 f3 = ((const float4*)(src + 32))[1];
        int4 w;
        w.x = pk4(f0.x*FP8SCALE, f0.y*FP8SCALE, f0.z*FP8SCALE, f0.w*FP8SCALE);
        w.y = pk4(f1.x*FP8SCALE, f1.y*FP8SCALE, f1.z*FP8SCALE, f1.w*FP8SCALE);
        w.z = pk4(f2.x*FP8SCALE, f2.y*FP8SCALE, f2.z*FP8SCALE, f2.w*FP8SCALE);
        w.w = pk4(f3.x*FP8SCALE, f3.y*FP8SCALE, f3.z*FP8SCALE, f3.w*FP8SCALE);
        ((int4*)(dst0 + (size_t)r * DIM))[sl] = w;
      }
      __threadfence();
      __syncthreads();
      if (tid == 0)
        __hip_atomic_store(flags + P, 1, __ATOMIC_RELEASE, __HIP_MEMORY_SCOPE_AGENT);
    }
  }

  // ---- wait: all rows normalized (producers are blocks 0..255, always first)
  if (tid == 0) {
    while (__hip_atomic_load(nctr, __ATOMIC_ACQUIRE, __HIP_MEMORY_SCOPE_AGENT) < NCONV)
      __builtin_amdgcn_s_sleep(16);
  }
  __syncthreads();

  // ---- read-side LDS offsets (R7 verbatim)
  int L = lane & 15;
  int g = lane >> 4;
  int phys = g ^ ((L >> 1) & 3);
  int offA = (wr * 64 + L) * 64 + phys * 16;   // bytes, + m*1024
  int offB = (wc * 64 + L) * 64 + phys * 16;   // bytes, + n*1024
  int sg = (tid & 3) ^ ((tid >> 3) & 3);       // staging k-slot involution

  union I4L { int4 v; long l[2]; };

  // ---- phase 2: gemm tiles via per-XCD tickets
  for (;;) {
    if (tid == 0) sh_t = atomicAdd(tctr + xcd, 1);
    __syncthreads();
    int t = sh_t;
    if (t >= 1024) break;
    int P = xcd * 128 + (t >> 3);
    int rowt = t & 7;
    int row0 = rowt * 128;
    if (tid == 0) {
      while (__hip_atomic_load(flags + P, __ATOMIC_ACQUIRE, __HIP_MEMORY_SCOPE_AGENT) == 0)
        __builtin_amdgcn_s_sleep(8);
    }
    __syncthreads();   // also fences LDS reuse across tiles (all waves past lgkm0)

    const u8* gA[2];
    const u8* gB[2];
    #pragma unroll
    for (int jj = 0; jj < 2; ++jj) {
      int r = jj * 64 + (tid >> 2);
      gA[jj] = xnb8 + (size_t)(row0 + r) * DIM + sg * 16;
      gB[jj] = memb8 + ((size_t)P * 128 + r) * DIM + sg * 16;
    }

    f32x4 acc[4][4];
    #pragma unroll
    for (int m = 0; m < 4; ++m)
      #pragma unroll
      for (int n = 0; n < 4; ++n) acc[m][n] = (f32x4){0.f, 0.f, 0.f, 0.f};

    auto stage = [&](int h) {
      int slot = h % 3;
      int ko = h * 64;
      #pragma unroll
      for (int jj = 0; jj < 2; ++jj) {
        gload_lds16(gA[jj] + ko, &As[slot][jj * 4096 + tid * 16]);
        gload_lds16(gB[jj] + ko, &Bs[slot][jj * 4096 + tid * 16]);
      }
    };

    auto body = [&](int h) {
      int slot = h % 3;
      const u8* Ab = &As[slot][0];
      const u8* Bb = &Bs[slot][0];
      I4L av[4], bv[4];
      #pragma unroll
      for (int m = 0; m < 4; ++m) av[m].v = *(const int4*)(Ab + offA + m * 1024);
      #pragma unroll
      for (int n = 0; n < 4; ++n) bv[n].v = *(const int4*)(Bb + offB + n * 1024);
      __builtin_amdgcn_s_setprio(1);
      #pragma unroll
      for (int m = 0; m < 4; ++m)
        #pragma unroll
        for (int n = 0; n < 4; ++n)
          acc[m][n] = __builtin_amdgcn_mfma_f32_16x16x32_fp8_fp8(
              av[m].l[0], bv[n].l[0], acc[m][n], 0, 0, 0);
      #pragma unroll
      for (int m = 0; m < 4; ++m)
        #pragma unroll
        for (int n = 0; n < 4; ++n)
          acc[m][n] = __builtin_amdgcn_mfma_f32_16x16x32_fp8_fp8(
              av[m].l[1], bv[n].l[1], acc[m][n], 0, 0, 0);
      __builtin_amdgcn_s_setprio(0);
    };

    stage(0);
    stage(1);
    for (int h = 0; h < 8; ++h) {
      if (h < 7) { S_VMCNT(4); }
      else { S_VMCNT(0); }
      S_BAR();
      if (h < 6) stage(h + 2);
      body(h);
      S_LGKM0();
    }

    // epilogue: D row=(lane>>4)*4+q, col=lane&15
    int rbase = row0 + wr * 64 + (lane >> 4) * 4;
    int cbase = P * 128 + wc * 64 + (lane & 15);
    #pragma unroll
    for (int m = 0; m < 4; ++m)
      #pragma unroll
      for (int n = 0; n < 4; ++n)
        #pragma unroll
        for (int q = 0; q < 4; ++q) {
          float v = acc[m][n][q];
          if (v > TAUS) {
            int grow = rbase + m * 16 + q;
            int gcol = cbase + n * 16;
            int idx = atomicAdd(&cnt[grow], 1);
            if (idx < CAP) ccol[(size_t)grow * CAP + idx] = gcol;
          }
        }
  }
}

// ------------------------------- exact rescore + top-32 + softmax vote
// (unchanged -- validated absmax 0.0 against the np reference)
__global__ __launch_bounds__(256) void rescore_vote(const float* __restrict__ xn,
                                                    const float* __restrict__ mem,
                                                    const int* __restrict__ labels,
                                                    const int* __restrict__ cnt,
                                                    const int* __restrict__ ccol,
                                                    float* __restrict__ out) {
  int row = blockIdx.x;
  int tid = threadIdx.x;
  int gid = tid >> 4;          // 16 groups
  int gl = tid & 15;           // lane within group
  __shared__ __attribute__((aligned(16))) float xs[DIM];
  __shared__ double sv[CAP];
  __shared__ int sc[CAP];
  __shared__ double selv[TOPK];
  __shared__ int selc[TOPK];
  __shared__ double wv32[TOPK];
  __shared__ int slab[TOPK];

  ((float2*)xs)[tid] = ((const float2*)(xn + (size_t)row * DIM))[tid];
  if (tid < TOPK) { selv[tid] = -1e300; selc[tid] = 0; }
  int count = cnt[row];
  if (count > CAP) count = CAP;
  __syncthreads();

  // dot phase: one 16-lane group per candidate, fp64 accumulate
  for (int c = gid; c < count; c += 16) {
    int col = ccol[(size_t)row * CAP + c];
    const float4* mp = (const float4*)(mem + (size_t)col * DIM);
    const float4* xp = (const float4*)xs;
    double p = 0.0;
    #pragma unroll
    for (int u = 0; u < 8; ++u) {
      float4 mv = mp[u * 16 + gl];
      float4 xv = xp[u * 16 + gl];
      p += (double)mv.x * xv.x + (double)mv.y * xv.y +
           (double)mv.z * xv.z + (double)mv.w * xv.w;
    }
    #pragma unroll
    for (int o = 8; o; o >>= 1) p += __shfl_xor(p, o);
    if (gl == 0) { sv[c] = p; sc[c] = col; }
  }
  __syncthreads();

  // rank-based top-32: rank = #{j: v_j > v or (v_j==v && col_j < col)}
  for (int c = tid; c < count; c += 256) {
    double v = sv[c]; int cc = sc[c];
    int r = 0;
    for (int j = 0; j < count; ++j) {
      double vj = sv[j]; int cj = sc[j];
      r += (vj > v) || (vj == v && cj < cc);
    }
    if (r < TOPK) { selv[r] = v; selc[r] = cc; }
  }
  __syncthreads();

  // softmax(sim/0.1) + one-hot vote
  if (tid < TOPK) {
    slab[tid] = labels[selc[tid]];
    double e = exp((selv[tid] - selv[0]) * 10.0);
    double s = e;
    #pragma unroll
    for (int o = 16; o; o >>= 1) s += __shfl_xor(s, o, 32);
    wv32[tid] = e / s;
  }
  __syncthreads();
  if (tid < NCLS) {
    double a = 0.0;
    #pragma unroll
    for (int k = 0; k < TOPK; ++k)
      if (slab[k] == tid) a += wv32[k];
    float r2 = (float)(a + 1e-5);
    out[(size_t)row * NCLS + tid] = fminf(r2, 1.0f);
  }
}

// ---------------------------------------------------------------------------
extern "C" void kernel_launch(void* const* d_in, const int* in_sizes, int n_in,
                              void* d_out, int out_size, void* d_ws, size_t ws_size,
                              hipStream_t stream) {
  const float* x = (const float*)d_in[0];
  const float* mem = (const float*)d_in[1];
  const int* labels = (const int*)d_in[2];
  float* out = (float*)d_out;
  char* ws = (char*)d_ws;

  // workspace layout (needs ~74 MB)
  u8* memb8 = (u8*)ws;                               //  67,108,864 B
  float* xn = (float*)(ws + 67108864);               //   2,097,152 B
  u8* xnb8 = (u8*)(ws + 69206016);                   //     524,288 B
  char* ctrl = ws + 69730304;                        //       8,704 B
  int* cnt = (int*)ctrl;                             // 1024 ints
  int* flags = (int*)(ctrl + 4096);                  // 1024 ints
  int* tctr = (int*)(ctrl + 8192);                   // 8 ints
  int* nctr = (int*)(ctrl + 8224);                   // 1 int
  int* ccol = (int*)(ws + 69739008);                 //   4,194,304 B

  hipMemsetAsync(ctrl, 0, 8704, stream);
  mega<<<dim3(GRID), dim3(256), 0, stream>>>(x, mem, xn, xnb8, memb8, cnt,
                                             ccol, flags, tctr, nctr);
  rescore_vote<<<dim3(B_ROWS), dim3(256), 0, stream>>>(xn, mem, labels, cnt,
                                                       ccol, out);
}

// Round 9
// 214.794 us; speedup vs baseline: 3.1319x; 3.1319x over previous
//
#include <hip/hip_runtime.h>

typedef unsigned short u16;
typedef unsigned char u8;
typedef __attribute__((ext_vector_type(4))) float f32x4;
typedef __attribute__((ext_vector_type(2))) unsigned short u16x2;

#define B_ROWS 1024
#define DIM 512
#define QN 131072
#define TOPK 32
#define NCLS 10
#define TAUS 35.84f   /* 0.14 * 256 (both operands scaled x16) */
#define CAP 1024
#define FP8SCALE 16.0f

#define S_VMCNT(N) asm volatile("s_waitcnt vmcnt(" #N ")" ::: "memory")
#define S_BAR() asm volatile("s_barrier" ::: "memory")
#define S_LGKM0() asm volatile("s_waitcnt lgkmcnt(0)" ::: "memory")

__device__ __forceinline__ void gload_lds16(const void* gsrc, void* ldst) {
  __builtin_amdgcn_global_load_lds(
      (const __attribute__((address_space(1))) void*)gsrc,
      (__attribute__((address_space(3))) void*)ldst, 16, 0, 0);
}

// pack 4 floats -> 4 fp8 e4m3 bytes (HW cvt). Same packer for A and B, so
// any byte-order convention cancels in the dot product.
__device__ __forceinline__ int pk4(float a, float b, float c, float d) {
  int w = __builtin_amdgcn_cvt_pk_fp8_f32(a, b, 0, false);
  w = __builtin_amdgcn_cvt_pk_fp8_f32(c, d, w, true);
  return w;
}

// ---------------------------------------------------------------- normalize x
// fp32 normalized row -> xn; fp8(x16) k-permuted row -> xnb8.
// Permuted layout per 64-k chunk c: 16B slot t = {k c*64+t*8..+8} ++
// {k c*64+32+t*8..+8}.
__global__ __launch_bounds__(256) void normalize_x(const float* __restrict__ x,
                                                   float* __restrict__ xn,
                                                   u8* __restrict__ xnb8) {
  int row = blockIdx.x;
  int tid = threadIdx.x;
  __shared__ float xs[DIM];
  __shared__ float wsum[4];
  float2 v = ((const float2*)(x + (size_t)row * DIM))[tid];
  float ss = v.x * v.x + v.y * v.y;
  #pragma unroll
  for (int o = 32; o; o >>= 1) ss += __shfl_xor(ss, o);
  if ((tid & 63) == 0) wsum[tid >> 6] = ss;
  __syncthreads();
  float tot = wsum[0] + wsum[1] + wsum[2] + wsum[3];
  float scale = 1.0f / fmaxf(sqrtf(tot), 1e-12f);
  float2 o2; o2.x = v.x * scale; o2.y = v.y * scale;
  ((float2*)(xn + (size_t)row * DIM))[tid] = o2;
  xs[2 * tid] = o2.x; xs[2 * tid + 1] = o2.y;
  __syncthreads();
  if (tid < 32) {  // 32 slots of 16B per row
    int c = tid >> 2, t4 = tid & 3;
    int k0 = c * 64 + t4 * 8;
    int4 w;
    w.x = pk4(xs[k0+0]*FP8SCALE, xs[k0+1]*FP8SCALE, xs[k0+2]*FP8SCALE, xs[k0+3]*FP8SCALE);
    w.y = pk4(xs[k0+4]*FP8SCALE, xs[k0+5]*FP8SCALE, xs[k0+6]*FP8SCALE, xs[k0+7]*FP8SCALE);
    w.z = pk4(xs[k0+32]*FP8SCALE, xs[k0+33]*FP8SCALE, xs[k0+34]*FP8SCALE, xs[k0+35]*FP8SCALE);
    w.w = pk4(xs[k0+36]*FP8SCALE, xs[k0+37]*FP8SCALE, xs[k0+38]*FP8SCALE, xs[k0+39]*FP8SCALE);
    ((int4*)(xnb8 + (size_t)row * DIM))[tid] = w;
  }
}

// ---------------------- fp8 MFMA GEMM + in-kernel B conversion + filter
// 128x128 tile, 4 waves, K-step = 64. A (fp8, tiny) staged via the R7-proven
// 3-slot gload_lds queue (prefetch distance 2). B staged from mem fp32
// DIRECTLY: 8x global_load_dwordx4 -> regs (issued 2 steps early), cvt_pk to
// fp8 -> ds_write_b128 into a 2-slot queue (written at step h for reads at
// h+1). The 256 MB fp32 B-stream rides under compute; the separate convert
// kernel (58 us + 67 MB write/read) is deleted.
// Race proof (one s_barrier per step):
//   - B(h+1) ds_written at step h (post-MFMA), read at h+1 after barrier;
//     WAR: slot (h+1)&1's previous readers (step h-1) retired before their
//     lgkm0 + barrier(h) < write. WAW trivially ordered per-thread.
//   - A(h+2) gload_lds issued AFTER barrier(h); previous readers of slot
//     (h+2)%3 were step h-1, retired pre-barrier(h).
//   - vmcnt by queue order: entry queue [PA(h+1)2, PB(h+1)8] -> vmcnt(8)
//     retires PA(h+1) (lands >=1 barrier before its reads). Mid queue
//     [PB(h+1)8, PA(h+2)2] -> vmcnt(2) retires PB(h+1) exactly (vmcnt(0)
//     at h=6 tail where PA(8) doesn't exist). Never a blind drain mid-loop.
// LDS swizzle involution unchanged from R6/R7 (measured 0 conflicts).
__global__ __launch_bounds__(256, 3) void gemm_filter(const u8* __restrict__ xnb8,
                                                      const float* __restrict__ mem,
                                                      int* __restrict__ cnt,
                                                      int* __restrict__ ccol) {
  __shared__ __attribute__((aligned(16))) u8 As[3][8192];
  __shared__ __attribute__((aligned(16))) u8 Bs[2][8192];
  int bid = blockIdx.x;
  int xcd = bid & 7;
  int i = bid >> 3;
  int colt = xcd * 128 + (i >> 3);
  int rowt = i & 7;
  int row0 = rowt * 128;
  int col0 = colt * 128;
  int tid = threadIdx.x;
  int lane = tid & 63;
  int wv = tid >> 6;
  int wr = wv >> 1, wc = wv & 1;

  // staging geometry: chunk jj covers row r = jj*64 + (tid>>2); logical
  // k-slot sg = (tid&3) ^ ((r>>1)&3) = (tid&3)^((tid>>3)&3)
  int sg = (tid & 3) ^ ((tid >> 3) & 3);
  const u8* gA[2];
  const float* gB[2];
  #pragma unroll
  for (int jj = 0; jj < 2; ++jj) {
    int r = jj * 64 + (tid >> 2);
    gA[jj] = xnb8 + (size_t)(row0 + r) * DIM + sg * 16;
    gB[jj] = mem + (size_t)(col0 + r) * DIM + sg * 8;
  }

  // read side (R7 verbatim)
  int L = lane & 15;
  int g = lane >> 4;
  int phys = g ^ ((L >> 1) & 3);
  int offA = (wr * 64 + L) * 64 + phys * 16;   // bytes, + m*1024
  int offB = (wc * 64 + L) * 64 + phys * 16;   // bytes, + n*1024

  f32x4 acc[4][4];
  #pragma unroll
  for (int m = 0; m < 4; ++m)
    #pragma unroll
    for (int n = 0; n < 4; ++n) acc[m][n] = (f32x4){0.f, 0.f, 0.f, 0.f};

  float4 pb[2][4];  // B prefetch regs: 2 chunks x 16 floats (32 VGPR)

  auto stageA = [&](int h) {
    int slot = h % 3;
    #pragma unroll
    for (int jj = 0; jj < 2; ++jj)
      gload_lds16(gA[jj] + h * 64, &As[slot][jj * 4096 + tid * 16]);
  };
  auto issuePB = [&](int h) {
    #pragma unroll
    for (int jj = 0; jj < 2; ++jj) {
      const float4* s = (const float4*)(gB[jj] + h * 64);
      pb[jj][0] = s[0];  pb[jj][1] = s[1];   // k sg*8..+8
      pb[jj][2] = s[8];  pb[jj][3] = s[9];   // k 32+sg*8..+8
    }
  };
  auto writeB = [&](int h) {
    int slot = h & 1;
    #pragma unroll
    for (int jj = 0; jj < 2; ++jj) {
      int4 w;
      w.x = pk4(pb[jj][0].x*FP8SCALE, pb[jj][0].y*FP8SCALE, pb[jj][0].z*FP8SCALE, pb[jj][0].w*FP8SCALE);
      w.y = pk4(pb[jj][1].x*FP8SCALE, pb[jj][1].y*FP8SCALE, pb[jj][1].z*FP8SCALE, pb[jj][1].w*FP8SCALE);
      w.z = pk4(pb[jj][2].x*FP8SCALE, pb[jj][2].y*FP8SCALE, pb[jj][2].z*FP8SCALE, pb[jj][2].w*FP8SCALE);
      w.w = pk4(pb[jj][3].x*FP8SCALE, pb[jj][3].y*FP8SCALE, pb[jj][3].z*FP8SCALE, pb[jj][3].w*FP8SCALE);
      *(int4*)&Bs[slot][jj * 4096 + tid * 16] = w;
    }
  };

  union I4L { int4 v; long l[2]; };

  // prologue
  stageA(0); stageA(1); issuePB(0);
  S_VMCNT(0);
  writeB(0);
  issuePB(1);
  S_LGKM0();

  #pragma unroll
  for (int h = 0; h < 8; ++h) {
    S_VMCNT(8);          // retires PA(h+1); no-op at h=0
    S_BAR();
    if (h < 6) stageA(h + 2);
    const u8* Ab = &As[h % 3][0];
    const u8* Bb = &Bs[h & 1][0];
    I4L av[4], bv[4];
    #pragma unroll
    for (int m = 0; m < 4; ++m) av[m].v = *(const int4*)(Ab + offA + m * 1024);
    #pragma unroll
    for (int n = 0; n < 4; ++n) bv[n].v = *(const int4*)(Bb + offB + n * 1024);
    __builtin_amdgcn_s_setprio(1);
    #pragma unroll
    for (int m = 0; m < 4; ++m)
      #pragma unroll
      for (int n = 0; n < 4; ++n)
        acc[m][n] = __builtin_amdgcn_mfma_f32_16x16x32_fp8_fp8(
            av[m].l[0], bv[n].l[0], acc[m][n], 0, 0, 0);
    #pragma unroll
    for (int m = 0; m < 4; ++m)
      #pragma unroll
      for (int n = 0; n < 4; ++n)
        acc[m][n] = __builtin_amdgcn_mfma_f32_16x16x32_fp8_fp8(
            av[m].l[1], bv[n].l[1], acc[m][n], 0, 0, 0);
    __builtin_amdgcn_s_setprio(0);
    if (h < 7) {
      if (h < 6) { S_VMCNT(2); }   // retires PB(h+1), leaves PA(h+2) flying
      else { S_VMCNT(0); }         // h=6: only PB(7) outstanding
      writeB(h + 1);
      if (h < 6) issuePB(h + 2);
      S_LGKM0();                   // ds_writes retired before next barrier
    }
  }

  // epilogue: D row=(lane>>4)*4+q, col=lane&15 (dtype-independent layout)
  int rbase = row0 + wr * 64 + (lane >> 4) * 4;
  int cbase = col0 + wc * 64 + (lane & 15);
  #pragma unroll
  for (int m = 0; m < 4; ++m)
    #pragma unroll
    for (int n = 0; n < 4; ++n)
      #pragma unroll
      for (int q = 0; q < 4; ++q) {
        float v = acc[m][n][q];
        if (v > TAUS) {
          int grow = rbase + m * 16 + q;
          int gcol = cbase + n * 16;
          int idx = atomicAdd(&cnt[grow], 1);
          if (idx < CAP) ccol[(size_t)grow * CAP + idx] = gcol;
        }
      }
}

// ------------------------------- exact rescore + top-32 + softmax vote
// (unchanged -- validated absmax 0.0 against the np reference)
__global__ __launch_bounds__(256) void rescore_vote(const float* __restrict__ xn,
                                                    const float* __restrict__ mem,
                                                    const int* __restrict__ labels,
                                                    const int* __restrict__ cnt,
                                                    const int* __restrict__ ccol,
                                                    float* __restrict__ out) {
  int row = blockIdx.x;
  int tid = threadIdx.x;
  int gid = tid >> 4;          // 16 groups
  int gl = tid & 15;           // lane within group
  __shared__ __attribute__((aligned(16))) float xs[DIM];
  __shared__ double sv[CAP];
  __shared__ int sc[CAP];
  __shared__ double selv[TOPK];
  __shared__ int selc[TOPK];
  __shared__ double wv32[TOPK];
  __shared__ int slab[TOPK];

  ((float2*)xs)[tid] = ((const float2*)(xn + (size_t)row * DIM))[tid];
  if (tid < TOPK) { selv[tid] = -1e300; selc[tid] = 0; }
  int count = cnt[row];
  if (count > CAP) count = CAP;
  __syncthreads();

  // dot phase: one 16-lane group per candidate, fp64 accumulate
  for (int c = gid; c < count; c += 16) {
    int col = ccol[(size_t)row * CAP + c];
    const float4* mp = (const float4*)(mem + (size_t)col * DIM);
    const float4* xp = (const float4*)xs;
    double p = 0.0;
    #pragma unroll
    for (int u = 0; u < 8; ++u) {
      float4 mv = mp[u * 16 + gl];
      float4 xv = xp[u * 16 + gl];
      p += (double)mv.x * xv.x + (double)mv.y * xv.y +
           (double)mv.z * xv.z + (double)mv.w * xv.w;
    }
    #pragma unroll
    for (int o = 8; o; o >>= 1) p += __shfl_xor(p, o);
    if (gl == 0) { sv[c] = p; sc[c] = col; }
  }
  __syncthreads();

  // rank-based top-32: rank = #{j: v_j > v or (v_j==v && col_j < col)}
  for (int c = tid; c < count; c += 256) {
    double v = sv[c]; int cc = sc[c];
    int r = 0;
    for (int j = 0; j < count; ++j) {
      double vj = sv[j]; int cj = sc[j];
      r += (vj > v) || (vj == v && cj < cc);
    }
    if (r < TOPK) { selv[r] = v; selc[r] = cc; }
  }
  __syncthreads();

  // softmax(sim/0.1) + one-hot vote
  if (tid < TOPK) {
    slab[tid] = labels[selc[tid]];
    double e = exp((selv[tid] - selv[0]) * 10.0);
    double s = e;
    #pragma unroll
    for (int o = 16; o; o >>= 1) s += __shfl_xor(s, o, 32);
    wv32[tid] = e / s;
  }
  __syncthreads();
  if (tid < NCLS) {
    double a = 0.0;
    #pragma unroll
    for (int k = 0; k < TOPK; ++k)
      if (slab[k] == tid) a += wv32[k];
    float r2 = (float)(a + 1e-5);
    out[(size_t)row * NCLS + tid] = fminf(r2, 1.0f);
  }
}

// ---------------------------------------------------------------------------
extern "C" void kernel_launch(void* const* d_in, const int* in_sizes, int n_in,
                              void* d_out, int out_size, void* d_ws, size_t ws_size,
                              hipStream_t stream) {
  const float* x = (const float*)d_in[0];
  const float* mem = (const float*)d_in[1];
  const int* labels = (const int*)d_in[2];
  float* out = (float*)d_out;
  char* ws = (char*)d_ws;

  // workspace layout (needs ~7 MB)
  float* xn = (float*)ws;                            //   2,097,152 B
  u8* xnb8 = (u8*)(ws + 2097152);                    //     524,288 B
  int* cnt = (int*)(ws + 2621440);                   //       4,096 B
  int* ccol = (int*)(ws + 2625536);                  //   4,194,304 B

  hipMemsetAsync(cnt, 0, B_ROWS * sizeof(int), stream);
  normalize_x<<<dim3(B_ROWS), dim3(256), 0, stream>>>(x, xn, xnb8);
  gemm_filter<<<dim3((B_ROWS / 128) * (QN / 128)), dim3(256), 0, stream>>>(
      xnb8, mem, cnt, ccol);
  rescore_vote<<<dim3(B_ROWS), dim3(256), 0, stream>>>(xn, mem, labels, cnt,
                                                       ccol, out);
}

// Round 10
// 214.506 us; speedup vs baseline: 3.1361x; 1.0013x over previous
//
#include <hip/hip_runtime.h>

typedef unsigned short u16;
typedef unsigned char u8;
typedef __attribute__((ext_vector_type(4))) float f32x4;

#define B_ROWS 1024
#define DIM 512
#define QN 131072
#define TOPK 32
#define NCLS 10
#define TAUS 35.84f   /* 0.14 * 256 (both operands scaled x16) */
#define CAP 1024
#define FP8SCALE 16.0f

#define S_VMCNT(N) asm volatile("s_waitcnt vmcnt(" #N ")" ::: "memory")
#define S_BAR() asm volatile("s_barrier" ::: "memory")
#define S_LGKM0() asm volatile("s_waitcnt lgkmcnt(0)" ::: "memory")

__device__ __forceinline__ void gload_lds16(const void* gsrc, void* ldst) {
  __builtin_amdgcn_global_load_lds(
      (const __attribute__((address_space(1))) void*)gsrc,
      (__attribute__((address_space(3))) void*)ldst, 16, 0, 0);
}

// pack 4 floats -> 4 fp8 e4m3 bytes (HW cvt). Same packer for A and B, so
// any byte-order convention cancels in the dot product.
__device__ __forceinline__ int pk4(float a, float b, float c, float d) {
  int w = __builtin_amdgcn_cvt_pk_fp8_f32(a, b, 0, false);
  w = __builtin_amdgcn_cvt_pk_fp8_f32(c, d, w, true);
  return w;
}

// ---------------------------------------------------------------- normalize x
// fp32 normalized row -> xn; fp8(x16) k-permuted row -> xnb8; also zeroes
// cnt[row] (memset fused -- one launch saved).
__global__ __launch_bounds__(256) void normalize_x(const float* __restrict__ x,
                                                   float* __restrict__ xn,
                                                   u8* __restrict__ xnb8,
                                                   int* __restrict__ cnt) {
  int row = blockIdx.x;
  int tid = threadIdx.x;
  __shared__ float xs[DIM];
  __shared__ float wsum[4];
  if (tid == 0) cnt[row] = 0;
  float2 v = ((const float2*)(x + (size_t)row * DIM))[tid];
  float ss = v.x * v.x + v.y * v.y;
  #pragma unroll
  for (int o = 32; o; o >>= 1) ss += __shfl_xor(ss, o);
  if ((tid & 63) == 0) wsum[tid >> 6] = ss;
  __syncthreads();
  float tot = wsum[0] + wsum[1] + wsum[2] + wsum[3];
  float scale = 1.0f / fmaxf(sqrtf(tot), 1e-12f);
  float2 o2; o2.x = v.x * scale; o2.y = v.y * scale;
  ((float2*)(xn + (size_t)row * DIM))[tid] = o2;
  xs[2 * tid] = o2.x; xs[2 * tid + 1] = o2.y;
  __syncthreads();
  if (tid < 32) {  // 32 slots of 16B per row (k-permuted fp8)
    int c = tid >> 2, t4 = tid & 3;
    int k0 = c * 64 + t4 * 8;
    int4 w;
    w.x = pk4(xs[k0+0]*FP8SCALE, xs[k0+1]*FP8SCALE, xs[k0+2]*FP8SCALE, xs[k0+3]*FP8SCALE);
    w.y = pk4(xs[k0+4]*FP8SCALE, xs[k0+5]*FP8SCALE, xs[k0+6]*FP8SCALE, xs[k0+7]*FP8SCALE);
    w.z = pk4(xs[k0+32]*FP8SCALE, xs[k0+33]*FP8SCALE, xs[k0+34]*FP8SCALE, xs[k0+35]*FP8SCALE);
    w.w = pk4(xs[k0+36]*FP8SCALE, xs[k0+37]*FP8SCALE, xs[k0+38]*FP8SCALE, xs[k0+39]*FP8SCALE);
    ((int4*)(xnb8 + (size_t)row * DIM))[tid] = w;
  }
}

// ---------------------- fp8 MFMA GEMM + in-kernel B conversion + filter
// R9 structure with A-queue 3->2 slots (prefetch distance 1): LDS 32 KiB ->
// 5 blocks/CU, deeper cross-block overlap (m114). A is 512 KB total and
// shared by all blocks -> L2-hit (~200cy), covered by one MFMA step.
// Queue order per step h (A-dist 1, B-dist 2):
//   pt1: vmcnt(E); s_barrier          E=8 (h<7) else 0
//   pt2: stageA(h+1)^2                [h<7]
//   pt3: ds_read A(h),B(h); MFMA
//   pt4: vmcnt(2); writeB(h+1) [h<7]; issuePB(h+2)^8 [h<6]; lgkm0
// Outstanding-queue enumeration: at pt1 [A(h)^2 retired by E... keeps
// PB(h+1)^8]; at pt4 [PB(h+1)^8, A(h+1)^2] -> vmcnt(2) retires PB(h+1)
// exactly (h=6: [PB(7)^8, A(7)^2] likewise). Tail: E=0 at h=7 covers A(7).
// WAR on A slot (h+1)&1: readers were step h-1, retired pre-barrier(h)
// (lgkm0 at h-1 pt4). WAW: A(h-1) vmcnt-retired at h-1 pt1 < issue at h pt2.
// LDS swizzle involution unchanged (measured 0 conflicts R6-R9).
__global__ __launch_bounds__(256, 3) void gemm_filter(const u8* __restrict__ xnb8,
                                                      const float* __restrict__ mem,
                                                      int* __restrict__ cnt,
                                                      int* __restrict__ ccol) {
  __shared__ __attribute__((aligned(16))) u8 As[2][8192];
  __shared__ __attribute__((aligned(16))) u8 Bs[2][8192];
  int bid = blockIdx.x;
  int xcd = bid & 7;
  int i = bid >> 3;
  int colt = xcd * 128 + (i >> 3);
  int rowt = i & 7;
  int row0 = rowt * 128;
  int col0 = colt * 128;
  int tid = threadIdx.x;
  int lane = tid & 63;
  int wv = tid >> 6;
  int wr = wv >> 1, wc = wv & 1;

  // staging geometry: chunk jj covers row r = jj*64 + (tid>>2); logical
  // k-slot sg = (tid&3) ^ ((r>>1)&3) = (tid&3)^((tid>>3)&3)
  int sg = (tid & 3) ^ ((tid >> 3) & 3);
  const u8* gA[2];
  const float* gB[2];
  #pragma unroll
  for (int jj = 0; jj < 2; ++jj) {
    int r = jj * 64 + (tid >> 2);
    gA[jj] = xnb8 + (size_t)(row0 + r) * DIM + sg * 16;
    gB[jj] = mem + (size_t)(col0 + r) * DIM + sg * 8;
  }

  // read side (R7 verbatim)
  int L = lane & 15;
  int g = lane >> 4;
  int phys = g ^ ((L >> 1) & 3);
  int offA = (wr * 64 + L) * 64 + phys * 16;   // bytes, + m*1024
  int offB = (wc * 64 + L) * 64 + phys * 16;   // bytes, + n*1024

  f32x4 acc[4][4];
  #pragma unroll
  for (int m = 0; m < 4; ++m)
    #pragma unroll
    for (int n = 0; n < 4; ++n) acc[m][n] = (f32x4){0.f, 0.f, 0.f, 0.f};

  float4 pb[2][4];  // B prefetch regs: 2 chunks x 16 floats (32 VGPR)

  auto stageA = [&](int h) {
    int slot = h & 1;
    #pragma unroll
    for (int jj = 0; jj < 2; ++jj)
      gload_lds16(gA[jj] + h * 64, &As[slot][jj * 4096 + tid * 16]);
  };
  auto issuePB = [&](int h) {
    #pragma unroll
    for (int jj = 0; jj < 2; ++jj) {
      const float4* s = (const float4*)(gB[jj] + h * 64);
      pb[jj][0] = s[0];  pb[jj][1] = s[1];   // k sg*8..+8
      pb[jj][2] = s[8];  pb[jj][3] = s[9];   // k 32+sg*8..+8
    }
  };
  auto writeB = [&](int h) {
    int slot = h & 1;
    #pragma unroll
    for (int jj = 0; jj < 2; ++jj) {
      int4 w;
      w.x = pk4(pb[jj][0].x*FP8SCALE, pb[jj][0].y*FP8SCALE, pb[jj][0].z*FP8SCALE, pb[jj][0].w*FP8SCALE);
      w.y = pk4(pb[jj][1].x*FP8SCALE, pb[jj][1].y*FP8SCALE, pb[jj][1].z*FP8SCALE, pb[jj][1].w*FP8SCALE);
      w.z = pk4(pb[jj][2].x*FP8SCALE, pb[jj][2].y*FP8SCALE, pb[jj][2].z*FP8SCALE, pb[jj][2].w*FP8SCALE);
      w.w = pk4(pb[jj][3].x*FP8SCALE, pb[jj][3].y*FP8SCALE, pb[jj][3].z*FP8SCALE, pb[jj][3].w*FP8SCALE);
      *(int4*)&Bs[slot][jj * 4096 + tid * 16] = w;
    }
  };

  union I4L { int4 v; long l[2]; };

  // prologue: A(0), B(0) resident; PB(1) in flight
  stageA(0); issuePB(0);
  S_VMCNT(0);
  writeB(0);
  issuePB(1);
  S_LGKM0();

  #pragma unroll
  for (int h = 0; h < 8; ++h) {
    if (h < 7) { S_VMCNT(8); }   // retires A(h); keeps PB(h+1) flying
    else { S_VMCNT(0); }         // h=7: drains A(7)
    S_BAR();
    if (h < 7) stageA(h + 1);
    const u8* Ab = &As[h & 1][0];
    const u8* Bb = &Bs[h & 1][0];
    I4L av[4], bv[4];
    #pragma unroll
    for (int m = 0; m < 4; ++m) av[m].v = *(const int4*)(Ab + offA + m * 1024);
    #pragma unroll
    for (int n = 0; n < 4; ++n) bv[n].v = *(const int4*)(Bb + offB + n * 1024);
    __builtin_amdgcn_s_setprio(1);
    #pragma unroll
    for (int m = 0; m < 4; ++m)
      #pragma unroll
      for (int n = 0; n < 4; ++n)
        acc[m][n] = __builtin_amdgcn_mfma_f32_16x16x32_fp8_fp8(
            av[m].l[0], bv[n].l[0], acc[m][n], 0, 0, 0);
    #pragma unroll
    for (int m = 0; m < 4; ++m)
      #pragma unroll
      for (int n = 0; n < 4; ++n)
        acc[m][n] = __builtin_amdgcn_mfma_f32_16x16x32_fp8_fp8(
            av[m].l[1], bv[n].l[1], acc[m][n], 0, 0, 0);
    __builtin_amdgcn_s_setprio(0);
    if (h < 7) {
      S_VMCNT(2);                // retires PB(h+1); keeps A(h+1) flying
      writeB(h + 1);
      if (h < 6) issuePB(h + 2);
      S_LGKM0();                 // ds ops retired before next barrier
    }
  }

  // epilogue: D row=(lane>>4)*4+q, col=lane&15 (dtype-independent layout)
  int rbase = row0 + wr * 64 + (lane >> 4) * 4;
  int cbase = col0 + wc * 64 + (lane & 15);
  #pragma unroll
  for (int m = 0; m < 4; ++m)
    #pragma unroll
    for (int n = 0; n < 4; ++n)
      #pragma unroll
      for (int q = 0; q < 4; ++q) {
        float v = acc[m][n][q];
        if (v > TAUS) {
          int grow = rbase + m * 16 + q;
          int gcol = cbase + n * 16;
          int idx = atomicAdd(&cnt[grow], 1);
          if (idx < CAP) ccol[(size_t)grow * CAP + idx] = gcol;
        }
      }
}

// ------------------------------- exact rescore + top-32 + softmax vote
// (unchanged -- validated absmax 0.0 against the np reference)
__global__ __launch_bounds__(256) void rescore_vote(const float* __restrict__ xn,
                                                    const float* __restrict__ mem,
                                                    const int* __restrict__ labels,
                                                    const int* __restrict__ cnt,
                                                    const int* __restrict__ ccol,
                                                    float* __restrict__ out) {
  int row = blockIdx.x;
  int tid = threadIdx.x;
  int gid = tid >> 4;          // 16 groups
  int gl = tid & 15;           // lane within group
  __shared__ __attribute__((aligned(16))) float xs[DIM];
  __shared__ double sv[CAP];
  __shared__ int sc[CAP];
  __shared__ double selv[TOPK];
  __shared__ int selc[TOPK];
  __shared__ double wv32[TOPK];
  __shared__ int slab[TOPK];

  ((float2*)xs)[tid] = ((const float2*)(xn + (size_t)row * DIM))[tid];
  if (tid < TOPK) { selv[tid] = -1e300; selc[tid] = 0; }
  int count = cnt[row];
  if (count > CAP) count = CAP;
  __syncthreads();

  // dot phase: one 16-lane group per candidate, fp64 accumulate
  for (int c = gid; c < count; c += 16) {
    int col = ccol[(size_t)row * CAP + c];
    const float4* mp = (const float4*)(mem + (size_t)col * DIM);
    const float4* xp = (const float4*)xs;
    double p = 0.0;
    #pragma unroll
    for (int u = 0; u < 8; ++u) {
      float4 mv = mp[u * 16 + gl];
      float4 xv = xp[u * 16 + gl];
      p += (double)mv.x * xv.x + (double)mv.y * xv.y +
           (double)mv.z * xv.z + (double)mv.w * xv.w;
    }
    #pragma unroll
    for (int o = 8; o; o >>= 1) p += __shfl_xor(p, o);
    if (gl == 0) { sv[c] = p; sc[c] = col; }
  }
  __syncthreads();

  // rank-based top-32: rank = #{j: v_j > v or (v_j==v && col_j < col)}
  for (int c = tid; c < count; c += 256) {
    double v = sv[c]; int cc = sc[c];
    int r = 0;
    for (int j = 0; j < count; ++j) {
      double vj = sv[j]; int cj = sc[j];
      r += (vj > v) || (vj == v && cj < cc);
    }
    if (r < TOPK) { selv[r] = v; selc[r] = cc; }
  }
  __syncthreads();

  // softmax(sim/0.1) + one-hot vote
  if (tid < TOPK) {
    slab[tid] = labels[selc[tid]];
    double e = exp((selv[tid] - selv[0]) * 10.0);
    double s = e;
    #pragma unroll
    for (int o = 16; o; o >>= 1) s += __shfl_xor(s, o, 32);
    wv32[tid] = e / s;
  }
  __syncthreads();
  if (tid < NCLS) {
    double a = 0.0;
    #pragma unroll
    for (int k = 0; k < TOPK; ++k)
      if (slab[k] == tid) a += wv32[k];
    float r2 = (float)(a + 1e-5);
    out[(size_t)row * NCLS + tid] = fminf(r2, 1.0f);
  }
}

// ---------------------------------------------------------------------------
extern "C" void kernel_launch(void* const* d_in, const int* in_sizes, int n_in,
                              void* d_out, int out_size, void* d_ws, size_t ws_size,
                              hipStream_t stream) {
  const float* x = (const float*)d_in[0];
  const float* mem = (const float*)d_in[1];
  const int* labels = (const int*)d_in[2];
  float* out = (float*)d_out;
  char* ws = (char*)d_ws;

  // workspace layout (needs ~7 MB)
  float* xn = (float*)ws;                            //   2,097,152 B
  u8* xnb8 = (u8*)(ws + 2097152);                    //     524,288 B
  int* cnt = (int*)(ws + 2621440);                   //       4,096 B
  int* ccol = (int*)(ws + 2625536);                  //   4,194,304 B

  normalize_x<<<dim3(B_ROWS), dim3(256), 0, stream>>>(x, xn, xnb8, cnt);
  gemm_filter<<<dim3((B_ROWS / 128) * (QN / 128)), dim3(256), 0, stream>>>(
      xnb8, mem, cnt, ccol);
  rescore_vote<<<dim3(B_ROWS), dim3(256), 0, stream>>>(xn, mem, labels, cnt,
                                                       ccol, out);
}

// Round 11
// 195.757 us; speedup vs baseline: 3.4365x; 1.0958x over previous
//
#include <hip/hip_runtime.h>

typedef unsigned short u16;
typedef unsigned char u8;
typedef __attribute__((ext_vector_type(4))) float f32x4;

#define B_ROWS 1024
#define DIM 512
#define QN 131072
#define TOPK 32
#define NCLS 10
#define TAUS 35.84f   /* 0.14 * 256 (both operands scaled x16) */
#define CAP 1024
#define FP8SCALE 16.0f

#define S_VMCNT(N) asm volatile("s_waitcnt vmcnt(" #N ")" ::: "memory")
#define S_BAR() asm volatile("s_barrier" ::: "memory")
#define S_LGKM0() asm volatile("s_waitcnt lgkmcnt(0)" ::: "memory")

__device__ __forceinline__ void gload_lds16(const void* gsrc, void* ldst) {
  __builtin_amdgcn_global_load_lds(
      (const __attribute__((address_space(1))) void*)gsrc,
      (__attribute__((address_space(3))) void*)ldst, 16, 0, 0);
}

// pack 4 floats -> 4 fp8 e4m3 bytes (HW cvt). Same packer for A and B, so
// any byte-order convention cancels in the dot product.
__device__ __forceinline__ int pk4(float a, float b, float c, float d) {
  int w = __builtin_amdgcn_cvt_pk_fp8_f32(a, b, 0, false);
  w = __builtin_amdgcn_cvt_pk_fp8_f32(c, d, w, true);
  return w;
}

// ---------------------------------------------------------------- normalize x
// fp32 normalized row -> xn; fp8(x16) k-permuted row -> xnb8; zeroes cnt.
__global__ __launch_bounds__(256) void normalize_x(const float* __restrict__ x,
                                                   float* __restrict__ xn,
                                                   u8* __restrict__ xnb8,
                                                   int* __restrict__ cnt) {
  int row = blockIdx.x;
  int tid = threadIdx.x;
  __shared__ float xs[DIM];
  __shared__ float wsum[4];
  if (tid == 0) cnt[row] = 0;
  float2 v = ((const float2*)(x + (size_t)row * DIM))[tid];
  float ss = v.x * v.x + v.y * v.y;
  #pragma unroll
  for (int o = 32; o; o >>= 1) ss += __shfl_xor(ss, o);
  if ((tid & 63) == 0) wsum[tid >> 6] = ss;
  __syncthreads();
  float tot = wsum[0] + wsum[1] + wsum[2] + wsum[3];
  float scale = 1.0f / fmaxf(sqrtf(tot), 1e-12f);
  float2 o2; o2.x = v.x * scale; o2.y = v.y * scale;
  ((float2*)(xn + (size_t)row * DIM))[tid] = o2;
  xs[2 * tid] = o2.x; xs[2 * tid + 1] = o2.y;
  __syncthreads();
  if (tid < 32) {  // 32 slots of 16B per row (k-permuted fp8)
    int c = tid >> 2, t4 = tid & 3;
    int k0 = c * 64 + t4 * 8;
    int4 w;
    w.x = pk4(xs[k0+0]*FP8SCALE, xs[k0+1]*FP8SCALE, xs[k0+2]*FP8SCALE, xs[k0+3]*FP8SCALE);
    w.y = pk4(xs[k0+4]*FP8SCALE, xs[k0+5]*FP8SCALE, xs[k0+6]*FP8SCALE, xs[k0+7]*FP8SCALE);
    w.z = pk4(xs[k0+32]*FP8SCALE, xs[k0+33]*FP8SCALE, xs[k0+34]*FP8SCALE, xs[k0+35]*FP8SCALE);
    w.w = pk4(xs[k0+36]*FP8SCALE, xs[k0+37]*FP8SCALE, xs[k0+38]*FP8SCALE, xs[k0+39]*FP8SCALE);
    ((int4*)(xnb8 + (size_t)row * DIM))[tid] = w;
  }
}

// ---------------------- fp8 MFMA GEMM + in-kernel B conversion + filter
// BM=256 x BN=64 tile, 4 waves (4M split: wave wv owns rows wv*64..+64, all
// waves share the 64-col B panel), K-step 64, 8 steps. Same pipeline
// skeleton as R9/R10 (proven): A via 2-slot gload_lds queue dist-1; B via
// reg-staged fp32->fp8 cvt, 2-slot ds_write queue dist-2. vs 128x128: B fp32
// stream halves (2GB->1GB), cvt_pk 16->8 and B-loads 8->4 per thread/step,
// pb regs 32->16.
// Queue enumeration per step h:
//   pt1: vmcnt(4) [retires A(h)x4, keeps PB(h+1)x4]; s_barrier   (h=7: 0)
//   pt2: stageA(h+1)x4                                           [h<7]
//   pt3: ds_read A(h)x4,B(h)x4; MFMA x32
//   pt4: vmcnt(4) [retires PB(h+1)x4, keeps A(h+1)x4]; writeB(h+1) [h<7];
//        issuePB(h+2)x4 [h<6]; lgkm0
// Race proofs identical in structure to R9 (fences: lgkm0-before-barrier for
// LDS WAR; vmcnt-retirement order for landing guarantees).
// LDS swizzle involution unchanged (0 conflicts measured R6-R10).
__global__ __launch_bounds__(256, 3) void gemm_filter(const u8* __restrict__ xnb8,
                                                      const float* __restrict__ mem,
                                                      int* __restrict__ cnt,
                                                      int* __restrict__ ccol) {
  __shared__ __attribute__((aligned(16))) u8 As[2][16384];
  __shared__ __attribute__((aligned(16))) u8 Bs[2][4096];
  int bid = blockIdx.x;
  // XCD-aware: the 4 row-sharers of a B-panel sit on one XCD
  int xcd = bid & 7;
  int i = bid >> 3;
  int colt = xcd * 256 + (i >> 2);
  int rowt = i & 3;
  int row0 = rowt * 256;
  int col0 = colt * 64;
  int tid = threadIdx.x;
  int lane = tid & 63;
  int wv = tid >> 6;

  // staging geometry: logical k-slot sg = (tid&3) ^ ((r>>1)&3); with
  // r = jj*64 + (tid>>2) (A) or r = tid>>2 (B), sg = (tid&3)^((tid>>3)&3).
  int sg = (tid & 3) ^ ((tid >> 3) & 3);
  const u8* gA[4];
  #pragma unroll
  for (int jj = 0; jj < 4; ++jj) {
    int r = jj * 64 + (tid >> 2);
    gA[jj] = xnb8 + (size_t)(row0 + r) * DIM + sg * 16;
  }
  const float* gB = mem + (size_t)(col0 + (tid >> 2)) * DIM + sg * 8;

  // read side: lane L = row-within-16; phys slot = g ^ ((L>>1)&3)
  int L = lane & 15;
  int g = lane >> 4;
  int phys = g ^ ((L >> 1) & 3);
  int offA = (wv * 64 + L) * 64 + phys * 16;   // bytes, + m*1024
  int offB = L * 64 + phys * 16;               // bytes, + n*1024

  f32x4 acc[4][4];
  #pragma unroll
  for (int m = 0; m < 4; ++m)
    #pragma unroll
    for (int n = 0; n < 4; ++n) acc[m][n] = (f32x4){0.f, 0.f, 0.f, 0.f};

  float4 pb[4];  // B prefetch regs: 16 floats (16 VGPR)

  auto stageA = [&](int h) {
    int slot = h & 1;
    #pragma unroll
    for (int jj = 0; jj < 4; ++jj)
      gload_lds16(gA[jj] + h * 64, &As[slot][jj * 4096 + tid * 16]);
  };
  auto issuePB = [&](int h) {
    const float4* s = (const float4*)(gB + h * 64);
    pb[0] = s[0]; pb[1] = s[1];   // k sg*8..+8
    pb[2] = s[8]; pb[3] = s[9];   // k 32+sg*8..+8
  };
  auto writeB = [&](int h) {
    int slot = h & 1;
    int4 w;
    w.x = pk4(pb[0].x*FP8SCALE, pb[0].y*FP8SCALE, pb[0].z*FP8SCALE, pb[0].w*FP8SCALE);
    w.y = pk4(pb[1].x*FP8SCALE, pb[1].y*FP8SCALE, pb[1].z*FP8SCALE, pb[1].w*FP8SCALE);
    w.z = pk4(pb[2].x*FP8SCALE, pb[2].y*FP8SCALE, pb[2].z*FP8SCALE, pb[2].w*FP8SCALE);
    w.w = pk4(pb[3].x*FP8SCALE, pb[3].y*FP8SCALE, pb[3].z*FP8SCALE, pb[3].w*FP8SCALE);
    *(int4*)&Bs[slot][tid * 16] = w;
  };

  union I4L { int4 v; long l[2]; };

  // prologue: A(0), B(0) resident; PB(1) in flight
  stageA(0); issuePB(0);
  S_VMCNT(0);
  writeB(0);
  issuePB(1);
  S_LGKM0();

  #pragma unroll
  for (int h = 0; h < 8; ++h) {
    if (h < 7) { S_VMCNT(4); }   // retires A(h); keeps PB(h+1) flying
    else { S_VMCNT(0); }         // h=7: drains A(7)
    S_BAR();
    if (h < 7) stageA(h + 1);
    const u8* Ab = &As[h & 1][0];
    const u8* Bb = &Bs[h & 1][0];
    I4L av[4], bv[4];
    #pragma unroll
    for (int m = 0; m < 4; ++m) av[m].v = *(const int4*)(Ab + offA + m * 1024);
    #pragma unroll
    for (int n = 0; n < 4; ++n) bv[n].v = *(const int4*)(Bb + offB + n * 1024);
    __builtin_amdgcn_s_setprio(1);
    #pragma unroll
    for (int m = 0; m < 4; ++m)
      #pragma unroll
      for (int n = 0; n < 4; ++n)
        acc[m][n] = __builtin_amdgcn_mfma_f32_16x16x32_fp8_fp8(
            av[m].l[0], bv[n].l[0], acc[m][n], 0, 0, 0);
    #pragma unroll
    for (int m = 0; m < 4; ++m)
      #pragma unroll
      for (int n = 0; n < 4; ++n)
        acc[m][n] = __builtin_amdgcn_mfma_f32_16x16x32_fp8_fp8(
            av[m].l[1], bv[n].l[1], acc[m][n], 0, 0, 0);
    __builtin_amdgcn_s_setprio(0);
    if (h < 7) {
      S_VMCNT(4);                // retires PB(h+1); keeps A(h+1) flying
      writeB(h + 1);
      if (h < 6) issuePB(h + 2);
      S_LGKM0();                 // ds ops retired before next barrier
    }
  }

  // epilogue: D row=(lane>>4)*4+q, col=lane&15 (dtype-independent layout)
  int rbase = row0 + wv * 64 + (lane >> 4) * 4;
  int cbase = col0 + (lane & 15);
  #pragma unroll
  for (int m = 0; m < 4; ++m)
    #pragma unroll
    for (int n = 0; n < 4; ++n)
      #pragma unroll
      for (int q = 0; q < 4; ++q) {
        float v = acc[m][n][q];
        if (v > TAUS) {
          int grow = rbase + m * 16 + q;
          int gcol = cbase + n * 16;
          int idx = atomicAdd(&cnt[grow], 1);
          if (idx < CAP) ccol[(size_t)grow * CAP + idx] = gcol;
        }
      }
}

// ------------------------------- exact rescore + top-32 + softmax vote
// (unchanged -- validated absmax 0.0 against the np reference)
__global__ __launch_bounds__(256) void rescore_vote(const float* __restrict__ xn,
                                                    const float* __restrict__ mem,
                                                    const int* __restrict__ labels,
                                                    const int* __restrict__ cnt,
                                                    const int* __restrict__ ccol,
                                                    float* __restrict__ out) {
  int row = blockIdx.x;
  int tid = threadIdx.x;
  int gid = tid >> 4;          // 16 groups
  int gl = tid & 15;           // lane within group
  __shared__ __attribute__((aligned(16))) float xs[DIM];
  __shared__ double sv[CAP];
  __shared__ int sc[CAP];
  __shared__ double selv[TOPK];
  __shared__ int selc[TOPK];
  __shared__ double wv32[TOPK];
  __shared__ int slab[TOPK];

  ((float2*)xs)[tid] = ((const float2*)(xn + (size_t)row * DIM))[tid];
  if (tid < TOPK) { selv[tid] = -1e300; selc[tid] = 0; }
  int count = cnt[row];
  if (count > CAP) count = CAP;
  __syncthreads();

  // dot phase: one 16-lane group per candidate, fp64 accumulate
  for (int c = gid; c < count; c += 16) {
    int col = ccol[(size_t)row * CAP + c];
    const float4* mp = (const float4*)(mem + (size_t)col * DIM);
    const float4* xp = (const float4*)xs;
    double p = 0.0;
    #pragma unroll
    for (int u = 0; u < 8; ++u) {
      float4 mv = mp[u * 16 + gl];
      float4 xv = xp[u * 16 + gl];
      p += (double)mv.x * xv.x + (double)mv.y * xv.y +
           (double)mv.z * xv.z + (double)mv.w * xv.w;
    }
    #pragma unroll
    for (int o = 8; o; o >>= 1) p += __shfl_xor(p, o);
    if (gl == 0) { sv[c] = p; sc[c] = col; }
  }
  __syncthreads();

  // rank-based top-32: rank = #{j: v_j > v or (v_j==v && col_j < col)}
  for (int c = tid; c < count; c += 256) {
    double v = sv[c]; int cc = sc[c];
    int r = 0;
    for (int j = 0; j < count; ++j) {
      double vj = sv[j]; int cj = sc[j];
      r += (vj > v) || (vj == v && cj < cc);
    }
    if (r < TOPK) { selv[r] = v; selc[r] = cc; }
  }
  __syncthreads();

  // softmax(sim/0.1) + one-hot vote
  if (tid < TOPK) {
    slab[tid] = labels[selc[tid]];
    double e = exp((selv[tid] - selv[0]) * 10.0);
    double s = e;
    #pragma unroll
    for (int o = 16; o; o >>= 1) s += __shfl_xor(s, o, 32);
    wv32[tid] = e / s;
  }
  __syncthreads();
  if (tid < NCLS) {
    double a = 0.0;
    #pragma unroll
    for (int k = 0; k < TOPK; ++k)
      if (slab[k] == tid) a += wv32[k];
    float r2 = (float)(a + 1e-5);
    out[(size_t)row * NCLS + tid] = fminf(r2, 1.0f);
  }
}

// ---------------------------------------------------------------------------
extern "C" void kernel_launch(void* const* d_in, const int* in_sizes, int n_in,
                              void* d_out, int out_size, void* d_ws, size_t ws_size,
                              hipStream_t stream) {
  const float* x = (const float*)d_in[0];
  const float* mem = (const float*)d_in[1];
  const int* labels = (const int*)d_in[2];
  float* out = (float*)d_out;
  char* ws = (char*)d_ws;

  // workspace layout (needs ~7 MB)
  float* xn = (float*)ws;                            //   2,097,152 B
  u8* xnb8 = (u8*)(ws + 2097152);                    //     524,288 B
  int* cnt = (int*)(ws + 2621440);                   //       4,096 B
  int* ccol = (int*)(ws + 2625536);                  //   4,194,304 B

  normalize_x<<<dim3(B_ROWS), dim3(256), 0, stream>>>(x, xn, xnb8, cnt);
  gemm_filter<<<dim3((B_ROWS / 256) * (QN / 64)), dim3(256), 0, stream>>>(
      xnb8, mem, cnt, ccol);
  rescore_vote<<<dim3(B_ROWS), dim3(256), 0, stream>>>(xn, mem, labels, cnt,
                                                       ccol, out);
}